// Round 11
// baseline (442.584 us; speedup 1.0000x reference)
//
#include <hip/hip_runtime.h>

#define WIRES   12
#define NSTATE  4096          // 2^12
#define QDEPTH  8
#define BLOCK   64            // ONE wave per block = one batch element
#define PER_T   64            // 6 local index bits; state in 128 VGPRs

using f2 = __attribute__((ext_vector_type(2))) float;

// Padded LDS layout: element i (0..4095) lives at f2-slot i + (i>>6)
// (row pitch 65). st[pad(a)] = amp[a].
__device__ __forceinline__ int pad(int i) { return i + (i >> 6); }

// Column j of the GF(2)-linear CNOT-ring permutation of layer l:
// F = g_0∘g_1∘...∘g_11 (g_11 applied first / innermost).
constexpr int colF(int l, int j) {
    int rr = (l % (WIRES - 1)) + 1;
    int v = 1 << j;
    for (int k = WIRES - 1; k >= 0; --k) {
        int bc = 11 - k;                   // control bit
        int bt = 11 - ((k + rr) % WIRES);  // target bit
        v ^= ((v >> bc) & 1) << bt;
    }
    return v;
}
struct ColsT { int v[QDEPTH][WIRES]; };
constexpr ColsT mkCols() {
    ColsT c{};
    for (int l = 0; l < QDEPTH; ++l)
        for (int j = 0; j < WIRES; ++j) c.v[l][j] = colF(l, j);
    return c;
}
static __device__ const ColsT COLS = mkCols();   // rodata, uniform s_load

// ---- setup kernel: 96 rotation matrices -> d_ws (8 f2 per gate) ----
// Entries pre-expanded for packed math: urr = {re,re}, uw = {-im,+im}.
__global__ void mats_kernel(const float* __restrict__ wts, f2* __restrict__ mg)
{
    int t = blockIdx.x * blockDim.x + threadIdx.x;
    if (t >= QDEPTH * WIRES) return;
    float phi   = tanhf(wts[t * 3 + 0]);
    float theta = tanhf(wts[t * 3 + 1]);
    float omega = tanhf(wts[t * 3 + 2]);
    float c  = cosf(theta * 0.5f);
    float s  = sinf(theta * 0.5f);
    float a  = 0.5f * (phi + omega);
    float bm = 0.5f * (phi - omega);
    float ca = cosf(a),  sa = sinf(a);
    float cb = cosf(bm), sb = sinf(bm);
    // U00 = (c*ca, -c*sa)  U01 = (-s*cb, -s*sb)
    // U10 = (s*cb, -s*sb)  U11 = (c*ca,  c*sa)
    f2* m = mg + t * 8;
    m[0] = f2{ c * ca,  c * ca};   // u00 re,re
    m[1] = f2{ c * sa, -c * sa};   // {-im,+im}, im=-c*sa
    m[2] = f2{-s * cb, -s * cb};   // u01 re,re
    m[3] = f2{ s * sb, -s * sb};   // {-im,+im}, im=-s*sb
    m[4] = f2{ s * cb,  s * cb};   // u10 re,re
    m[5] = f2{ s * sb, -s * sb};   // {-im,+im}, im=-s*sb
    m[6] = f2{ c * ca,  c * ca};   // u11 re,re
    m[7] = f2{-c * sa,  c * sa};   // {-im,+im}, im=+c*sa
}

// In-register 2x2 complex gate on local bit P (R7's proven interleaved asm:
// 4 chains round-robin, dependent pk-ops 8 issue-cycles apart).
template<int P>
__device__ __forceinline__ void gate(f2 r[PER_T], const f2* __restrict__ m)
{
    const f2 u00r = m[0], u00w = m[1], u01r = m[2], u01w = m[3];
    const f2 u10r = m[4], u10w = m[5], u11r = m[6], u11w = m[7];
    #pragma unroll
    for (int pr = 0; pr < PER_T / 2; pr += 2) {
        const int k0 = ((pr >> P) << (P + 1)) | (pr & ((1 << P) - 1));
        const int k1 = k0 | (1 << P);
        const int q  = pr + 1;
        const int j0 = ((q >> P) << (P + 1)) | (q & ((1 << P) - 1));
        const int j1 = j0 | (1 << P);
        f2 a0, b0, a1, b1;
        asm("v_pk_mul_f32 %0, %4, %8\n\t"
            "v_pk_mul_f32 %1, %4, %12\n\t"
            "v_pk_mul_f32 %2, %6, %8\n\t"
            "v_pk_mul_f32 %3, %6, %12\n\t"
            "v_pk_fma_f32 %0, %4, %9, %0 op_sel:[1,0,0] op_sel_hi:[0,1,1]\n\t"
            "v_pk_fma_f32 %1, %4, %13, %1 op_sel:[1,0,0] op_sel_hi:[0,1,1]\n\t"
            "v_pk_fma_f32 %2, %6, %9, %2 op_sel:[1,0,0] op_sel_hi:[0,1,1]\n\t"
            "v_pk_fma_f32 %3, %6, %13, %3 op_sel:[1,0,0] op_sel_hi:[0,1,1]\n\t"
            "v_pk_fma_f32 %0, %5, %10, %0\n\t"
            "v_pk_fma_f32 %1, %5, %14, %1\n\t"
            "v_pk_fma_f32 %2, %7, %10, %2\n\t"
            "v_pk_fma_f32 %3, %7, %14, %3\n\t"
            "v_pk_fma_f32 %0, %5, %11, %0 op_sel:[1,0,0] op_sel_hi:[0,1,1]\n\t"
            "v_pk_fma_f32 %1, %5, %15, %1 op_sel:[1,0,0] op_sel_hi:[0,1,1]\n\t"
            "v_pk_fma_f32 %2, %7, %11, %2 op_sel:[1,0,0] op_sel_hi:[0,1,1]\n\t"
            "v_pk_fma_f32 %3, %7, %15, %3 op_sel:[1,0,0] op_sel_hi:[0,1,1]"
            : "=&v"(a0), "=&v"(b0), "=&v"(a1), "=&v"(b1)
            : "v"(r[k0]), "v"(r[k1]), "v"(r[j0]), "v"(r[j1]),
              "v"(u00r), "v"(u00w), "v"(u01r), "v"(u01w),
              "v"(u10r), "v"(u10w), "v"(u11r), "v"(u11w));
        r[k0] = a0; r[k1] = b0; r[j0] = a1; r[j1] = b1;
    }
}

// Cross-lane 2x2 complex gate on LANE bit J via __shfl_xor (proven correct
// in R9). CHUNKED 8 amps at a time with sched_barrier fences so the
// scheduler cannot hoist all 128 bpermutes and blow the register budget
// (R9: VGPR 256 + spill). Live shfl temps <= 16.
template<int J>
__device__ __forceinline__ void lane_gate(f2 r[PER_T], const f2* __restrict__ m,
                                          int lane)
{
    const bool hib = (lane >> J) & 1;
    // recover (re,im) from the pre-expanded form: re = m[2e].x, im = m[2e+1].y
    const float ar = hib ? m[6].x : m[0].x;
    const float ai = hib ? m[7].y : m[1].y;
    const float br = hib ? m[4].x : m[2].x;
    const float bi = hib ? m[5].y : m[3].y;
    #pragma unroll
    for (int c = 0; c < 8; ++c) {
        float ox[8], oy[8];
        #pragma unroll
        for (int t = 0; t < 8; ++t) {
            ox[t] = __shfl_xor(r[c * 8 + t].x, 1 << J);
            oy[t] = __shfl_xor(r[c * 8 + t].y, 1 << J);
        }
        #pragma unroll
        for (int t = 0; t < 8; ++t) {
            const int k = c * 8 + t;
            const float mx = r[k].x, my = r[k].y;
            const float nx = ar * mx - ai * my + br * ox[t] - bi * oy[t];
            const float ny = ar * my + ai * mx + br * oy[t] + bi * ox[t];
            r[k] = f2{nx, ny};
        }
        __builtin_amdgcn_sched_barrier(0);   // cap live ranges per chunk
    }
}

// One wave = one batch element; state canonical all layer:
// r[k] = amp[(lane<<6)|k]. Per layer: 6 in-reg gates (wires 6..11, local
// bits) + 6 shfl_xor gates (wires 0..5, lane bits) + ONE LDS round-trip
// for the CNOT permutation F. No __syncthreads anywhere.
__global__ __launch_bounds__(BLOCK, 1) void qsim_kernel(
    const float* __restrict__ x,
    const f2*    __restrict__ mats_g,
    const int*   __restrict__ reps_ptr,
    float*       __restrict__ out,
    int write_mode)
{
    __shared__ f2 st[65 * 64];                           // 33280 B

    const int lane = threadIdx.x;
    const int b    = blockIdx.x;

    // ---- coalesced load of x, staged via LDS as packed real pairs ----
    const float4* xb4 = (const float4*)(x + (size_t)b * NSTATE);
    #pragma unroll
    for (int c = 0; c < 16; ++c) {
        int g = c * BLOCK + lane;            // coalesced float4 index
        float4 v = xb4[g];
        st[pad(2 * g)]     = f2{v.x, v.y};   // pair p = amps(2p,2p+1) reals
        st[pad(2 * g + 1)] = f2{v.z, v.w};
    }
    f2 r[PER_T];
    #pragma unroll
    for (int m = 0; m < 32; ++m) {
        f2 pr2 = st[pad((lane << 5) | m)];
        r[2*m]   = f2{pr2.x, 0.f};
        r[2*m+1] = f2{pr2.y, 0.f};
    }

    const int reps = reps_ptr[0];
    for (int rep = 0; rep < reps; ++rep) {
        #pragma unroll 1
        for (int l = 0; l < QDEPTH; ++l) {
            const f2* M = mats_g + l * WIRES * 8;   // wave-uniform -> s_load

            // wires 6..11 on local bits (P = 11-w)
            gate<5>(r, M + 6*8);  gate<4>(r, M + 7*8);
            gate<3>(r, M + 8*8);  gate<2>(r, M + 9*8);
            gate<1>(r, M + 10*8); gate<0>(r, M + 11*8);

            // wires 0..5 on lane bits (J = 5-w), in-place via shfl_xor
            lane_gate<5>(r, M + 0*8, lane);
            lane_gate<4>(r, M + 1*8, lane);
            lane_gate<3>(r, M + 2*8, lane);
            lane_gate<2>(r, M + 3*8, lane);
            lane_gate<1>(r, M + 4*8, lane);
            lane_gate<0>(r, M + 5*8, lane);

            // CNOT ring: write canonical, gather with F back to canonical
            #pragma unroll
            for (int k = 0; k < PER_T; ++k) st[65 * lane + k] = r[k];

            const int c0 = COLS.v[l][0], c1 = COLS.v[l][1], c2 = COLS.v[l][2];
            const int c3 = COLS.v[l][3], c4 = COLS.v[l][4], c5 = COLS.v[l][5];
            int Ft = 0;
            #pragma unroll
            for (int j = 0; j < 6; ++j)
                Ft ^= ((lane >> j) & 1) ? COLS.v[l][6 + j] : 0;
            #pragma unroll
            for (int k = 0; k < PER_T; ++k) {
                int ck = ((k & 1)  ? c0 : 0) ^ ((k & 2)  ? c1 : 0) ^
                         ((k & 4)  ? c2 : 0) ^ ((k & 8)  ? c3 : 0) ^
                         ((k & 16) ? c4 : 0) ^ ((k & 32) ? c5 : 0);
                r[k] = st[pad(Ft ^ ck)];
            }
            // r[k] = amp_after_layer[(lane<<6)|k]  (canonical again)
        }
    }

    // ---- write out ----
    if (write_mode == 0) {
        // harness views complex output as float32 real part
        #pragma unroll
        for (int m = 0; m < 32; ++m)
            st[pad((lane << 5) | m)] = f2{r[2*m].x, r[2*m+1].x};
        float4* ob4 = (float4*)(out + (size_t)b * NSTATE);
        #pragma unroll
        for (int c = 0; c < 16; ++c) {
            int g = c * BLOCK + lane;
            f2 a  = st[pad(2 * g)];
            f2 b2 = st[pad(2 * g + 1)];
            ob4[g] = make_float4(a.x, a.y, b2.x, b2.y);
        }
    } else {
        float2* ob = (float2*)out + (size_t)b * NSTATE;
        #pragma unroll
        for (int k = 0; k < PER_T; ++k)
            ob[(lane << 6) | k] = make_float2(r[k].x, r[k].y);
    }
}

extern "C" void kernel_launch(void* const* d_in, const int* in_sizes, int n_in,
                              void* d_out, int out_size, void* d_ws, size_t ws_size,
                              hipStream_t stream) {
    const float* x    = (const float*)d_in[0];
    const float* wts  = (const float*)d_in[1];
    const int*   reps = (const int*)d_in[2];
    float*       out  = (float*)d_out;
    f2*          mg   = (f2*)d_ws;            // 96 gates * 8 f2 = 3 KB scratch
    (void)in_sizes; (void)n_in; (void)ws_size;

    const int write_mode = (out_size >= 2 * 1024 * NSTATE) ? 1 : 0;

    mats_kernel<<<1, 128, 0, stream>>>(wts, mg);
    qsim_kernel<<<1024, BLOCK, 0, stream>>>(x, mg, reps, out, write_mode);
}

// Round 12
// 171.313 us; speedup vs baseline: 2.5835x; 2.5835x over previous
//
#include <hip/hip_runtime.h>

#define WIRES   12
#define NSTATE  4096          // 2^12
#define QDEPTH  8
#define BLOCK   128           // TWO waves per block = one batch element
#define PER_T   32            // 5 local index bits; state in 64 VGPRs
#define PITCH   33            // LDS row pitch (f2) for the 128x32 buffer

using f2 = __attribute__((ext_vector_type(2))) float;

// amp a lives at LDS f2-slot s(a) = PITCH*(a>>5) + (a&31)
__device__ __forceinline__ int slotA(int a) { return PITCH * (a >> 5) + (a & 31); }
// staging slot for pair index q (pitch 17 per 16)
__device__ __forceinline__ int sl(int q) { return q + (q >> 4); }

// Column j of the GF(2)-linear CNOT-ring permutation of layer l:
// F = g_0∘g_1∘...∘g_11 (g_11 applied first / innermost).
constexpr int colF(int l, int j) {
    int rr = (l % (WIRES - 1)) + 1;
    int v = 1 << j;
    for (int k = WIRES - 1; k >= 0; --k) {
        int bc = 11 - k;                   // control bit
        int bt = 11 - ((k + rr) % WIRES);  // target bit
        v ^= ((v >> bc) & 1) << bt;
    }
    return v;
}
struct ColsT { int v[QDEPTH][WIRES]; };
constexpr ColsT mkCols() {
    ColsT c{};
    for (int l = 0; l < QDEPTH; ++l)
        for (int j = 0; j < WIRES; ++j) c.v[l][j] = colF(l, j);
    return c;
}
static __device__ const ColsT COLS = mkCols();   // rodata, uniform s_load

// ---- setup kernel: 96 rotation matrices -> d_ws (8 f2 per gate) ----
// Entries pre-expanded for packed math: urr = {re,re}, uw = {-im,+im}.
__global__ void mats_kernel(const float* __restrict__ wts, f2* __restrict__ mg)
{
    int t = blockIdx.x * blockDim.x + threadIdx.x;
    if (t >= QDEPTH * WIRES) return;
    float phi   = tanhf(wts[t * 3 + 0]);
    float theta = tanhf(wts[t * 3 + 1]);
    float omega = tanhf(wts[t * 3 + 2]);
    float c  = cosf(theta * 0.5f);
    float s  = sinf(theta * 0.5f);
    float a  = 0.5f * (phi + omega);
    float bm = 0.5f * (phi - omega);
    float ca = cosf(a),  sa = sinf(a);
    float cb = cosf(bm), sb = sinf(bm);
    // U00 = (c*ca, -c*sa)  U01 = (-s*cb, -s*sb)
    // U10 = (s*cb, -s*sb)  U11 = (c*ca,  c*sa)
    f2* m = mg + t * 8;
    m[0] = f2{ c * ca,  c * ca};   // u00 re,re
    m[1] = f2{ c * sa, -c * sa};   // {-im,+im}, im=-c*sa
    m[2] = f2{-s * cb, -s * cb};   // u01 re,re
    m[3] = f2{ s * sb, -s * sb};   // {-im,+im}, im=-s*sb
    m[4] = f2{ s * cb,  s * cb};   // u10 re,re
    m[5] = f2{ s * sb, -s * sb};   // {-im,+im}, im=-s*sb
    m[6] = f2{ c * ca,  c * ca};   // u11 re,re
    m[7] = f2{-c * sa,  c * sa};   // {-im,+im}, im=+c*sa
}

// In-register 2x2 complex gate on local bit P (proven interleaved asm:
// 4 chains round-robin, dependent pk-ops 8 issue-cycles apart).
template<int P>
__device__ __forceinline__ void gate(f2 r[PER_T], const f2* __restrict__ m)
{
    const f2 u00r = m[0], u00w = m[1], u01r = m[2], u01w = m[3];
    const f2 u10r = m[4], u10w = m[5], u11r = m[6], u11w = m[7];
    #pragma unroll
    for (int pr = 0; pr < PER_T / 2; pr += 2) {
        const int k0 = ((pr >> P) << (P + 1)) | (pr & ((1 << P) - 1));
        const int k1 = k0 | (1 << P);
        const int q  = pr + 1;
        const int j0 = ((q >> P) << (P + 1)) | (q & ((1 << P) - 1));
        const int j1 = j0 | (1 << P);
        f2 a0, b0, a1, b1;
        asm("v_pk_mul_f32 %0, %4, %8\n\t"
            "v_pk_mul_f32 %1, %4, %12\n\t"
            "v_pk_mul_f32 %2, %6, %8\n\t"
            "v_pk_mul_f32 %3, %6, %12\n\t"
            "v_pk_fma_f32 %0, %4, %9, %0 op_sel:[1,0,0] op_sel_hi:[0,1,1]\n\t"
            "v_pk_fma_f32 %1, %4, %13, %1 op_sel:[1,0,0] op_sel_hi:[0,1,1]\n\t"
            "v_pk_fma_f32 %2, %6, %9, %2 op_sel:[1,0,0] op_sel_hi:[0,1,1]\n\t"
            "v_pk_fma_f32 %3, %6, %13, %3 op_sel:[1,0,0] op_sel_hi:[0,1,1]\n\t"
            "v_pk_fma_f32 %0, %5, %10, %0\n\t"
            "v_pk_fma_f32 %1, %5, %14, %1\n\t"
            "v_pk_fma_f32 %2, %7, %10, %2\n\t"
            "v_pk_fma_f32 %3, %7, %14, %3\n\t"
            "v_pk_fma_f32 %0, %5, %11, %0 op_sel:[1,0,0] op_sel_hi:[0,1,1]\n\t"
            "v_pk_fma_f32 %1, %5, %15, %1 op_sel:[1,0,0] op_sel_hi:[0,1,1]\n\t"
            "v_pk_fma_f32 %2, %7, %11, %2 op_sel:[1,0,0] op_sel_hi:[0,1,1]\n\t"
            "v_pk_fma_f32 %3, %7, %15, %3 op_sel:[1,0,0] op_sel_hi:[0,1,1]"
            : "=&v"(a0), "=&v"(b0), "=&v"(a1), "=&v"(b1)
            : "v"(r[k0]), "v"(r[k1]), "v"(r[j0]), "v"(r[j1]),
              "v"(u00r), "v"(u00w), "v"(u01r), "v"(u01w),
              "v"(u10r), "v"(u10w), "v"(u11r), "v"(u11w));
        r[k0] = a0; r[k1] = b0; r[j0] = a1; r[j1] = b1;
    }
}

// Cross-lane 2x2 complex gate on lane-xor MASK via __shfl_xor (concept
// proven in R9). 32-amp state + 8-amp chunks -> small live set, no fences.
template<int MASK>
__device__ __forceinline__ void lane_gate(f2 r[PER_T], const f2* __restrict__ m,
                                          int lane)
{
    const bool hib = (lane & MASK) != 0;
    // recover (re,im) from pre-expanded form: re = m[2e].x, im = m[2e+1].y
    const float ar = hib ? m[6].x : m[0].x;
    const float ai = hib ? m[7].y : m[1].y;
    const float br = hib ? m[4].x : m[2].x;
    const float bi = hib ? m[5].y : m[3].y;
    #pragma unroll
    for (int c = 0; c < PER_T / 8; ++c) {
        float ox[8], oy[8];
        #pragma unroll
        for (int t = 0; t < 8; ++t) {
            ox[t] = __shfl_xor(r[c * 8 + t].x, MASK);
            oy[t] = __shfl_xor(r[c * 8 + t].y, MASK);
        }
        #pragma unroll
        for (int t = 0; t < 8; ++t) {
            const int k = c * 8 + t;
            const float mx = r[k].x, my = r[k].y;
            const float nx = ar * mx - ai * my + br * ox[t] - bi * oy[t];
            const float ny = ar * my + ai * mx + br * oy[t] + bi * ox[t];
            r[k] = f2{nx, ny};
        }
    }
}

// Two waves = one batch element; 32 amps/thread.
// Canonical: r[k] = amp[(t<<5)|k]  (t = threadIdx, 7 bits; k 5 bits).
// Layer: 5 in-reg gates (wires 7..11, amp bits 4..0) -> LDS remap to
// r[k]=amp[(k<<7)|((t&3)<<5)|(t>>2)] (amp bits 11..7 local; bits 6,5 on
// lane bits t1,t0) -> 5 in-reg gates (wires 0..4) + 2 shfl gates (wires
// 5,6) -> store + F-gather back to canonical. 2 waves/SIMD hide latency.
__global__ __launch_bounds__(BLOCK, 2) void qsim_kernel(
    const float* __restrict__ x,
    const f2*    __restrict__ mats_g,
    const int*   __restrict__ reps_ptr,
    float*       __restrict__ out,
    int write_mode)
{
    __shared__ f2 st[PITCH * 128];                       // 33792 B

    const int t    = threadIdx.x;
    const int lane = t & 63;
    const int b    = blockIdx.x;

    // ---- coalesced load of x, staged via LDS as packed real pairs ----
    const float4* xb4 = (const float4*)(x + (size_t)b * NSTATE);
    #pragma unroll
    for (int c = 0; c < 8; ++c) {
        int g = c * BLOCK + t;               // coalesced float4 index [0,1024)
        float4 v = xb4[g];
        st[sl(2 * g)]     = f2{v.x, v.y};    // pair q = reals of amps 2q,2q+1
        st[sl(2 * g + 1)] = f2{v.z, v.w};
    }
    __syncthreads();
    f2 r[PER_T];
    #pragma unroll
    for (int m = 0; m < 16; ++m) {
        f2 pr2 = st[sl((t << 4) | m)];
        r[2*m]   = f2{pr2.x, 0.f};
        r[2*m+1] = f2{pr2.y, 0.f};
    }
    __syncthreads();

    const int reps = reps_ptr[0];
    for (int rep = 0; rep < reps; ++rep) {
        #pragma unroll 1
        for (int l = 0; l < QDEPTH; ++l) {
            const f2* M = mats_g + l * WIRES * 8;   // wave-uniform -> s_load

            // Phase A: wires 7..11 on local bits 4..0 (bit = 11-wire)
            gate<4>(r, M + 7*8);  gate<3>(r, M + 8*8);
            gate<2>(r, M + 9*8);  gate<1>(r, M + 10*8);
            gate<0>(r, M + 11*8);

            // RT1: store canonical, read remapped
            #pragma unroll
            for (int k = 0; k < PER_T; ++k) st[PITCH * t + k] = r[k];
            __syncthreads();
            #pragma unroll
            for (int k = 0; k < PER_T; ++k)
                r[k] = st[PITCH * ((k << 2) | (t & 3)) + ((t >> 2) & 31)];
            // now r[k] = amp[(k<<7) | ((t&3)<<5) | (t>>2)]

            // Phase B: wires 0..4 on local bits 4..0 (local bit P = amp bit
            // 7+P = wire 4-P)
            gate<4>(r, M + 0*8); gate<3>(r, M + 1*8);
            gate<2>(r, M + 2*8); gate<1>(r, M + 3*8);
            gate<0>(r, M + 4*8);

            // Phase C: wire 5 on amp bit 6 = lane bit 1; wire 6 on amp bit 5
            // = lane bit 0 (both intra-wave)
            lane_gate<2>(r, M + 5*8, lane);
            lane_gate<1>(r, M + 6*8, lane);

            __syncthreads();   // all RT1 reads done before overwrite
            // RT2: store in remapped layout at amp-slots
            #pragma unroll
            for (int k = 0; k < PER_T; ++k)
                st[PITCH * ((k << 2) | (t & 3)) + ((t >> 2) & 31)] = r[k];
            __syncthreads();

            // Gather: r[k] = amp[F((t<<5)|k)]  (back to canonical)
            const int c0 = COLS.v[l][0], c1 = COLS.v[l][1], c2 = COLS.v[l][2];
            const int c3 = COLS.v[l][3], c4 = COLS.v[l][4];
            int Ft = 0;
            #pragma unroll
            for (int j = 0; j < 7; ++j)
                Ft ^= ((t >> j) & 1) ? COLS.v[l][5 + j] : 0;
            #pragma unroll
            for (int k = 0; k < PER_T; ++k) {
                int A = Ft ^ (((k & 1)  ? c0 : 0) ^ ((k & 2)  ? c1 : 0) ^
                              ((k & 4)  ? c2 : 0) ^ ((k & 8)  ? c3 : 0) ^
                              ((k & 16) ? c4 : 0));
                r[k] = st[slotA(A)];
            }
            __syncthreads();   // gather done before next overwrite
        }
    }

    // ---- write out ----
    if (write_mode == 0) {
        // harness views complex output as float32 real part
        #pragma unroll
        for (int m = 0; m < 16; ++m)
            st[sl((t << 4) | m)] = f2{r[2*m].x, r[2*m+1].x};
        __syncthreads();
        float4* ob4 = (float4*)(out + (size_t)b * NSTATE);
        #pragma unroll
        for (int c = 0; c < 8; ++c) {
            int g = c * BLOCK + t;
            f2 a  = st[sl(2 * g)];
            f2 b2 = st[sl(2 * g + 1)];
            ob4[g] = make_float4(a.x, a.y, b2.x, b2.y);
        }
    } else {
        float2* ob = (float2*)out + (size_t)b * NSTATE;
        #pragma unroll
        for (int k = 0; k < PER_T; ++k)
            ob[(t << 5) | k] = make_float2(r[k].x, r[k].y);
    }
}

extern "C" void kernel_launch(void* const* d_in, const int* in_sizes, int n_in,
                              void* d_out, int out_size, void* d_ws, size_t ws_size,
                              hipStream_t stream) {
    const float* x    = (const float*)d_in[0];
    const float* wts  = (const float*)d_in[1];
    const int*   reps = (const int*)d_in[2];
    float*       out  = (float*)d_out;
    f2*          mg   = (f2*)d_ws;            // 96 gates * 8 f2 = 3 KB scratch
    (void)in_sizes; (void)n_in; (void)ws_size;

    const int write_mode = (out_size >= 2 * 1024 * NSTATE) ? 1 : 0;

    mats_kernel<<<1, 128, 0, stream>>>(wts, mg);
    qsim_kernel<<<1024, BLOCK, 0, stream>>>(x, mg, reps, out, write_mode);
}

// Round 13
// 167.611 us; speedup vs baseline: 2.6405x; 1.0221x over previous
//
#include <hip/hip_runtime.h>

#define WIRES   12
#define NSTATE  4096          // 2^12
#define QDEPTH  8
#define BLOCK   128           // TWO waves per block = one batch element
#define PER_T   32            // 5 local index bits; state in 64 VGPRs
#define PITCH   33            // LDS row pitch (f2) for the 128x32 buffer

using f2 = __attribute__((ext_vector_type(2))) float;

// Rotate low-5-bits left by 2: lifts lo-bits 1:0 into bank-pair bits 3:2 so
// BOTH the canonical (hi=t) and remapped (hi low2 = t&3, lo = t>>2) access
// patterns are bank-group bijective (16 distinct pairs per 16-lane group).
__device__ __forceinline__ int rot5(int x) { return ((x << 2) | (x >> 3)) & 31; }
// amp a lives at LDS f2-slot 33*(a>>5) + rot5(a&31)
__device__ __forceinline__ int slotA(int a) { return PITCH * (a >> 5) + rot5(a & 31); }
// staging slot for pair index q (pitch 17 per 16) — used once at load/store
__device__ __forceinline__ int sl(int q) { return q + (q >> 4); }

// Column j of the GF(2)-linear CNOT-ring permutation of layer l:
// F = g_0∘g_1∘...∘g_11 (g_11 applied first / innermost).
constexpr int colF(int l, int j) {
    int rr = (l % (WIRES - 1)) + 1;
    int v = 1 << j;
    for (int k = WIRES - 1; k >= 0; --k) {
        int bc = 11 - k;                   // control bit
        int bt = 11 - ((k + rr) % WIRES);  // target bit
        v ^= ((v >> bc) & 1) << bt;
    }
    return v;
}
struct ColsT { int v[QDEPTH][WIRES]; };
constexpr ColsT mkCols() {
    ColsT c{};
    for (int l = 0; l < QDEPTH; ++l)
        for (int j = 0; j < WIRES; ++j) c.v[l][j] = colF(l, j);
    return c;
}
static __device__ const ColsT COLS = mkCols();   // rodata, uniform s_load

// ---- setup kernel: 96 rotation matrices -> d_ws (8 f2 per gate) ----
// Entries pre-expanded for packed math: urr = {re,re}, uw = {-im,+im}.
__global__ void mats_kernel(const float* __restrict__ wts, f2* __restrict__ mg)
{
    int t = blockIdx.x * blockDim.x + threadIdx.x;
    if (t >= QDEPTH * WIRES) return;
    float phi   = tanhf(wts[t * 3 + 0]);
    float theta = tanhf(wts[t * 3 + 1]);
    float omega = tanhf(wts[t * 3 + 2]);
    float c  = cosf(theta * 0.5f);
    float s  = sinf(theta * 0.5f);
    float a  = 0.5f * (phi + omega);
    float bm = 0.5f * (phi - omega);
    float ca = cosf(a),  sa = sinf(a);
    float cb = cosf(bm), sb = sinf(bm);
    // U00 = (c*ca, -c*sa)  U01 = (-s*cb, -s*sb)
    // U10 = (s*cb, -s*sb)  U11 = (c*ca,  c*sa)
    f2* m = mg + t * 8;
    m[0] = f2{ c * ca,  c * ca};   // u00 re,re
    m[1] = f2{ c * sa, -c * sa};   // {-im,+im}, im=-c*sa
    m[2] = f2{-s * cb, -s * cb};   // u01 re,re
    m[3] = f2{ s * sb, -s * sb};   // {-im,+im}, im=-s*sb
    m[4] = f2{ s * cb,  s * cb};   // u10 re,re
    m[5] = f2{ s * sb, -s * sb};   // {-im,+im}, im=-s*sb
    m[6] = f2{ c * ca,  c * ca};   // u11 re,re
    m[7] = f2{-c * sa,  c * sa};   // {-im,+im}, im=+c*sa
}

// In-register 2x2 complex gate on local bit P (proven interleaved asm:
// 4 chains round-robin, dependent pk-ops spaced >= pipe latency).
template<int P>
__device__ __forceinline__ void gate(f2 r[PER_T], const f2* __restrict__ m)
{
    const f2 u00r = m[0], u00w = m[1], u01r = m[2], u01w = m[3];
    const f2 u10r = m[4], u10w = m[5], u11r = m[6], u11w = m[7];
    #pragma unroll
    for (int pr = 0; pr < PER_T / 2; pr += 2) {
        const int k0 = ((pr >> P) << (P + 1)) | (pr & ((1 << P) - 1));
        const int k1 = k0 | (1 << P);
        const int q  = pr + 1;
        const int j0 = ((q >> P) << (P + 1)) | (q & ((1 << P) - 1));
        const int j1 = j0 | (1 << P);
        f2 a0, b0, a1, b1;
        asm("v_pk_mul_f32 %0, %4, %8\n\t"
            "v_pk_mul_f32 %1, %4, %12\n\t"
            "v_pk_mul_f32 %2, %6, %8\n\t"
            "v_pk_mul_f32 %3, %6, %12\n\t"
            "v_pk_fma_f32 %0, %4, %9, %0 op_sel:[1,0,0] op_sel_hi:[0,1,1]\n\t"
            "v_pk_fma_f32 %1, %4, %13, %1 op_sel:[1,0,0] op_sel_hi:[0,1,1]\n\t"
            "v_pk_fma_f32 %2, %6, %9, %2 op_sel:[1,0,0] op_sel_hi:[0,1,1]\n\t"
            "v_pk_fma_f32 %3, %6, %13, %3 op_sel:[1,0,0] op_sel_hi:[0,1,1]\n\t"
            "v_pk_fma_f32 %0, %5, %10, %0\n\t"
            "v_pk_fma_f32 %1, %5, %14, %1\n\t"
            "v_pk_fma_f32 %2, %7, %10, %2\n\t"
            "v_pk_fma_f32 %3, %7, %14, %3\n\t"
            "v_pk_fma_f32 %0, %5, %11, %0 op_sel:[1,0,0] op_sel_hi:[0,1,1]\n\t"
            "v_pk_fma_f32 %1, %5, %15, %1 op_sel:[1,0,0] op_sel_hi:[0,1,1]\n\t"
            "v_pk_fma_f32 %2, %7, %11, %2 op_sel:[1,0,0] op_sel_hi:[0,1,1]\n\t"
            "v_pk_fma_f32 %3, %7, %15, %3 op_sel:[1,0,0] op_sel_hi:[0,1,1]"
            : "=&v"(a0), "=&v"(b0), "=&v"(a1), "=&v"(b1)
            : "v"(r[k0]), "v"(r[k1]), "v"(r[j0]), "v"(r[j1]),
              "v"(u00r), "v"(u00w), "v"(u01r), "v"(u01w),
              "v"(u10r), "v"(u10w), "v"(u11r), "v"(u11w));
        r[k0] = a0; r[k1] = b0; r[j0] = a1; r[j1] = b1;
    }
}

// Cross-lane 2x2 complex gate on lane-xor MASK via __shfl_xor (proven in
// R9/R11). 32-amp state + 8-amp chunks -> small live set, no spill.
template<int MASK>
__device__ __forceinline__ void lane_gate(f2 r[PER_T], const f2* __restrict__ m,
                                          int lane)
{
    const bool hib = (lane & MASK) != 0;
    const float ar = hib ? m[6].x : m[0].x;
    const float ai = hib ? m[7].y : m[1].y;
    const float br = hib ? m[4].x : m[2].x;
    const float bi = hib ? m[5].y : m[3].y;
    #pragma unroll
    for (int c = 0; c < PER_T / 8; ++c) {
        float ox[8], oy[8];
        #pragma unroll
        for (int t = 0; t < 8; ++t) {
            ox[t] = __shfl_xor(r[c * 8 + t].x, MASK);
            oy[t] = __shfl_xor(r[c * 8 + t].y, MASK);
        }
        #pragma unroll
        for (int t = 0; t < 8; ++t) {
            const int k = c * 8 + t;
            const float mx = r[k].x, my = r[k].y;
            const float nx = ar * mx - ai * my + br * ox[t] - bi * oy[t];
            const float ny = ar * my + ai * mx + br * oy[t] + bi * ox[t];
            r[k] = f2{nx, ny};
        }
    }
}

// Two waves = one batch element; 32 amps/thread.
// Canonical: r[k] = amp[(t<<5)|k]. Layer: 5 in-reg gates (wires 7..11) ->
// LDS remap (amp bits 11..7 local, bits 6,5 on lane bits) -> 5 in-reg
// gates (wires 0..4) + 2 shfl gates (wires 5,6) -> store + F-gather back
// to canonical. rot5 slot hash keeps every structured access bank-bijective.
__global__ __launch_bounds__(BLOCK, 2) void qsim_kernel(
    const float* __restrict__ x,
    const f2*    __restrict__ mats_g,
    const int*   __restrict__ reps_ptr,
    float*       __restrict__ out,
    int write_mode)
{
    __shared__ f2 st[PITCH * 128];                       // 33792 B

    const int t    = threadIdx.x;
    const int lane = t & 63;
    const int b    = blockIdx.x;

    // ---- coalesced load of x, staged via LDS as packed real pairs ----
    const float4* xb4 = (const float4*)(x + (size_t)b * NSTATE);
    #pragma unroll
    for (int c = 0; c < 8; ++c) {
        int g = c * BLOCK + t;               // coalesced float4 index [0,1024)
        float4 v = xb4[g];
        st[sl(2 * g)]     = f2{v.x, v.y};    // pair q = reals of amps 2q,2q+1
        st[sl(2 * g + 1)] = f2{v.z, v.w};
    }
    __syncthreads();
    f2 r[PER_T];
    #pragma unroll
    for (int m = 0; m < 16; ++m) {
        f2 pr2 = st[sl((t << 4) | m)];
        r[2*m]   = f2{pr2.x, 0.f};
        r[2*m+1] = f2{pr2.y, 0.f};
    }
    __syncthreads();

    const int rlo = rot5((t >> 2) & 31);     // remap-row low part, per thread

    const int reps = reps_ptr[0];
    for (int rep = 0; rep < reps; ++rep) {
        #pragma unroll 1
        for (int l = 0; l < QDEPTH; ++l) {
            const f2* M = mats_g + l * WIRES * 8;   // wave-uniform -> s_load

            // Phase A: wires 7..11 on local bits 4..0 (bit = 11-wire)
            gate<4>(r, M + 7*8);  gate<3>(r, M + 8*8);
            gate<2>(r, M + 9*8);  gate<1>(r, M + 10*8);
            gate<0>(r, M + 11*8);

            // RT1: store canonical (slot = 33*t + rot5(k), k folds to imm)
            #pragma unroll
            for (int k = 0; k < PER_T; ++k) st[PITCH * t + rot5(k)] = r[k];
            __syncthreads();
            #pragma unroll
            for (int k = 0; k < PER_T; ++k)
                r[k] = st[PITCH * ((k << 2) | (t & 3)) + rlo];
            // now r[k] = amp[(k<<7) | ((t&3)<<5) | (t>>2)]

            // Phase B: wires 0..4 on local bits 4..0
            gate<4>(r, M + 0*8); gate<3>(r, M + 1*8);
            gate<2>(r, M + 2*8); gate<1>(r, M + 3*8);
            gate<0>(r, M + 4*8);

            // Phase C: wire 5 on amp bit 6 = lane bit 1; wire 6 on amp bit 5
            // = lane bit 0 (both intra-wave)
            lane_gate<2>(r, M + 5*8, lane);
            lane_gate<1>(r, M + 6*8, lane);

            __syncthreads();   // all RT1 reads done before overwrite
            // RT2: store in remapped layout at amp-slots
            #pragma unroll
            for (int k = 0; k < PER_T; ++k)
                st[PITCH * ((k << 2) | (t & 3)) + rlo] = r[k];
            __syncthreads();

            // Gather: r[k] = amp[F((t<<5)|k)]  (back to canonical)
            const int c0 = COLS.v[l][0], c1 = COLS.v[l][1], c2 = COLS.v[l][2];
            const int c3 = COLS.v[l][3], c4 = COLS.v[l][4];
            int Ft = 0;
            #pragma unroll
            for (int j = 0; j < 7; ++j)
                Ft ^= ((t >> j) & 1) ? COLS.v[l][5 + j] : 0;
            #pragma unroll
            for (int k = 0; k < PER_T; ++k) {
                int A = Ft ^ (((k & 1)  ? c0 : 0) ^ ((k & 2)  ? c1 : 0) ^
                              ((k & 4)  ? c2 : 0) ^ ((k & 8)  ? c3 : 0) ^
                              ((k & 16) ? c4 : 0));
                r[k] = st[slotA(A)];
            }
            __syncthreads();   // gather done before next overwrite
        }
    }

    // ---- write out ----
    if (write_mode == 0) {
        // harness views complex output as float32 real part
        #pragma unroll
        for (int m = 0; m < 16; ++m)
            st[sl((t << 4) | m)] = f2{r[2*m].x, r[2*m+1].x};
        __syncthreads();
        float4* ob4 = (float4*)(out + (size_t)b * NSTATE);
        #pragma unroll
        for (int c = 0; c < 8; ++c) {
            int g = c * BLOCK + t;
            f2 a  = st[sl(2 * g)];
            f2 b2 = st[sl(2 * g + 1)];
            ob4[g] = make_float4(a.x, a.y, b2.x, b2.y);
        }
    } else {
        float2* ob = (float2*)out + (size_t)b * NSTATE;
        #pragma unroll
        for (int k = 0; k < PER_T; ++k)
            ob[(t << 5) | k] = make_float2(r[k].x, r[k].y);
    }
}

extern "C" void kernel_launch(void* const* d_in, const int* in_sizes, int n_in,
                              void* d_out, int out_size, void* d_ws, size_t ws_size,
                              hipStream_t stream) {
    const float* x    = (const float*)d_in[0];
    const float* wts  = (const float*)d_in[1];
    const int*   reps = (const int*)d_in[2];
    float*       out  = (float*)d_out;
    f2*          mg   = (f2*)d_ws;            // 96 gates * 8 f2 = 3 KB scratch
    (void)in_sizes; (void)n_in; (void)ws_size;

    const int write_mode = (out_size >= 2 * 1024 * NSTATE) ? 1 : 0;

    mats_kernel<<<1, 128, 0, stream>>>(wts, mg);
    qsim_kernel<<<1024, BLOCK, 0, stream>>>(x, mg, reps, out, write_mode);
}